// Round 6
// baseline (776.974 us; speedup 1.0000x reference)
//
#include <hip/hip_runtime.h>
#include <cstdint>
#include <cstddef>

#define NN 100000
#define NE 1600000
#define FEAT 140
#define EMB 64
#define HID 128
#define LN_EPS 1e-5f
#define SCAN_NBLK 98   // ceil(NN/1024)

typedef unsigned int uint;
typedef unsigned short ushort;
typedef unsigned char uchar;
using short8 = __attribute__((ext_vector_type(8))) short;
using f32x4  = __attribute__((ext_vector_type(4))) float;

__device__ __forceinline__ float gelu_exact(float x) {
    return 0.5f * x * (1.0f + erff(x * 0.70710678118654752440f));
}

__device__ __forceinline__ ushort f2bf(float f) {
    uint u = __float_as_uint(f);
    uint r = (u + 0x7fff + ((u >> 16) & 1)) >> 16;
    return (ushort)r;
}

__device__ __forceinline__ float bf2f(ushort u) {
    return __uint_as_float(((uint)u) << 16);
}

// ---- fp8 e4m3fn (flush-to-zero below 2^-6, RNE, clamp at 448) ----
__device__ __forceinline__ uchar f2fp8(float f) {
    uint u = __float_as_uint(f);
    uint s = (u >> 24) & 0x80u;
    uint t = u & 0x7fffffffu;
    if (t >= 0x43E00000u) return (uchar)(s | 0x7Eu);   // clamp to 448
    uint lsb = (t >> 20) & 1u;
    t += 0x7FFFFu + lsb;                               // RNE at bit 20
    uint e = t >> 23;
    if (e < 121u) return (uchar)s;                     // < 2^-6 -> +-0
    return (uchar)(s | ((e - 120u) << 3) | ((t >> 20) & 7u));
}

// decode 2 fp8 packed in low 16 bits of u
__device__ __forceinline__ void fp8pair(uint u, float& x, float& y) {
    uint b0 = u & 0xffu, b1 = (u >> 8) & 0xffu;
    uint e0 = b0 & 0x7fu, e1 = b1 & 0x7fu;
    uint s0 = (b0 & 0x80u) << 24, s1 = (b1 & 0x80u) << 24;
    x = __uint_as_float(e0 ? (s0 | ((e0 + 960u) << 20)) : s0);
    y = __uint_as_float(e1 ? (s1 | ((e1 + 960u) << 20)) : s1);
}

// ================= weight packing into MFMA B-fragment order =================
__global__ __launch_bounds__(256) void pack_weights_kernel(
    const float* __restrict__ W_in, const float* __restrict__ Wl,
    const float* __restrict__ Wr,
    ushort* __restrict__ winp, ushort* __restrict__ wcat)
{
    const int tid = blockIdx.x * 256 + threadIdx.x;
    const int NIN = 7 * 8 * 64;        // 3584
    const int NL  = 8 * 8 * 64;        // 4096
    if (tid < NIN) {
        const int kk = tid >> 9;
        const int c  = (tid >> 6) & 7;
        const int l  = tid & 63;
        const int kbase = kk * 32 + (l >> 4) * 8;
        const int col = c * 16 + (l & 15);
        short8 v;
        #pragma unroll
        for (int j = 0; j < 8; ++j) {
            const int k = kbase + j;
            v[j] = (k < 205) ? (short)f2bf(W_in[k * 128 + col]) : (short)0;
        }
        *(short8*)(winp + (size_t)tid * 8) = v;
    } else if (tid < NIN + 4 * NL) {
        const int t2 = tid - NIN;
        const int layer = t2 >> 12;
        const int r = t2 & (NL - 1);
        const int kk = r >> 9;
        const int c  = (r >> 6) & 7;
        const int l  = r & 63;
        const int kbase = kk * 32 + (l >> 4) * 8;
        const int col = c * 16 + (l & 15);
        short8 v;
        #pragma unroll
        for (int j = 0; j < 8; ++j) {
            const int k = kbase + j;
            const float x = (k < 128)
                ? Wl[(size_t)layer * 16384 + k * 128 + col]
                : Wr[(size_t)layer * 16384 + (k - 128) * 128 + col];
            v[j] = (short)f2bf(x);
        }
        *(short8*)(wcat + (size_t)t2 * 8) = v;
    }
}

// ================= input projection (MFMA) =================
__global__ __launch_bounds__(256) void input_proj_mfma(
    const float* __restrict__ nf, const float* __restrict__ topo,
    const float* __restrict__ embed, const int* __restrict__ opcode,
    const ushort* __restrict__ Wp, const float* __restrict__ b_in,
    const float* __restrict__ g0, const float* __restrict__ b0,
    float* __restrict__ h_out, ushort* __restrict__ hb_out,
    uchar* __restrict__ h8_out)
{
    __shared__ ushort xs[64 * 232];
    const int t = threadIdx.x;
    const int node0 = blockIdx.x * 64;

    for (int idx = t; idx < 64 * 35; idx += 256) {
        const int row = idx / 35, c = idx - row * 35;
        const int node = min(node0 + row, NN - 1);
        const float4 v = ((const float4*)nf)[(size_t)node * 35 + c];
        ushort* p = &xs[row * 232 + c * 4];
        p[0] = f2bf(v.x); p[1] = f2bf(v.y); p[2] = f2bf(v.z); p[3] = f2bf(v.w);
    }
    for (int idx = t; idx < 64 * 16; idx += 256) {
        const int row = idx >> 4, c = idx & 15;
        const int node = min(node0 + row, NN - 1);
        int op = opcode[node];
        op = min(max(op, 0), 127);
        const float4 v = ((const float4*)embed)[op * 16 + c];
        ushort* p = &xs[row * 232 + 140 + c * 4];
        p[0] = f2bf(v.x); p[1] = f2bf(v.y); p[2] = f2bf(v.z); p[3] = f2bf(v.w);
    }
    if (t < 64) {
        const int node = min(node0 + t, NN - 1);
        xs[t * 232 + 204] = f2bf(topo[node]);
    }
    for (int idx = t; idx < 64 * 19; idx += 256) {
        const int row = idx / 19, c = 205 + (idx - row * 19);
        xs[row * 232 + c] = 0;
    }
    __syncthreads();

    const int w = t >> 6, l = t & 63;
    const int gq = l >> 4, li = l & 15;

    f32x4 acc[8];
    #pragma unroll
    for (int c = 0; c < 8; ++c) acc[c] = (f32x4){0.f, 0.f, 0.f, 0.f};

    const short8* Bp = (const short8*)Wp;
    for (int kk = 0; kk < 7; ++kk) {
        const short8 a = *(const short8*)&xs[(w * 16 + li) * 232 + kk * 32 + gq * 8];
        #pragma unroll
        for (int c = 0; c < 8; ++c) {
            const short8 b = Bp[(kk * 8 + c) * 64 + l];
            acc[c] = __builtin_amdgcn_mfma_f32_16x16x32_bf16(a, b, acc[c], 0, 0, 0);
        }
    }

    float bias[8], gam[8], bet[8];
    #pragma unroll
    for (int c = 0; c < 8; ++c) {
        bias[c] = b_in[c * 16 + li];
        gam[c]  = g0[c * 16 + li];
        bet[c]  = b0[c * 16 + li];
    }
    float s[4] = {0, 0, 0, 0}, q[4] = {0, 0, 0, 0};
    #pragma unroll
    for (int c = 0; c < 8; ++c)
        #pragma unroll
        for (int r = 0; r < 4; ++r) {
            const float u = acc[c][r] + bias[c];
            acc[c][r] = u;
            s[r] += u;
            q[r] += u * u;
        }
    #pragma unroll
    for (int off = 1; off < 16; off <<= 1)
        #pragma unroll
        for (int r = 0; r < 4; ++r) {
            s[r] += __shfl_xor(s[r], off);
            q[r] += __shfl_xor(q[r], off);
        }
    #pragma unroll
    for (int r = 0; r < 4; ++r) {
        const int node = node0 + w * 16 + gq * 4 + r;
        if (node >= NN) continue;
        const float mean = s[r] * (1.0f / HID);
        const float var  = q[r] * (1.0f / HID) - mean * mean;
        const float rstd = rsqrtf(var + LN_EPS);
        #pragma unroll
        for (int c = 0; c < 8; ++c) {
            const float y = gelu_exact((acc[c][r] - mean) * rstd * gam[c] + bet[c]);
            h_out[(size_t)node * 128 + c * 16 + li] = y;
            hb_out[(size_t)node * 128 + c * 16 + li] = f2bf(y);
            h8_out[(size_t)node * 128 + c * 16 + li] = f2fp8(y);
        }
    }
}

// ================= CSR build =================
__global__ __launch_bounds__(256) void degree_int_kernel(const int* __restrict__ tgt,
                                                         int* __restrict__ deg) {
    const int e = blockIdx.x * 256 + threadIdx.x;
    if (e < NE) atomicAdd(&deg[tgt[e]], 1);
}

__global__ __launch_bounds__(1024) void deg_reduce_kernel(const int* __restrict__ deg,
                                                          int* __restrict__ bsum) {
    const int i = blockIdx.x * 1024 + threadIdx.x;
    int v = (i < NN) ? deg[i] : 0;
    #pragma unroll
    for (int off = 32; off >= 1; off >>= 1) v += __shfl_down(v, off);
    __shared__ int wsum[16];
    const int lane = threadIdx.x & 63, wid = threadIdx.x >> 6;
    if (lane == 0) wsum[wid] = v;
    __syncthreads();
    if (threadIdx.x < 16) {
        int s = wsum[threadIdx.x];
        #pragma unroll
        for (int off = 8; off >= 1; off >>= 1) s += __shfl_down(s, off, 16);
        if (threadIdx.x == 0) bsum[blockIdx.x] = s;
    }
}

__global__ __launch_bounds__(128) void bsum_scan_kernel(const int* __restrict__ bsum,
                                                        int* __restrict__ boff,
                                                        int* __restrict__ offs) {
    __shared__ int s_[128];
    const int t = threadIdx.x;
    int v = (t < SCAN_NBLK) ? bsum[t] : 0;
    s_[t] = v;
    __syncthreads();
    for (int off = 1; off < 128; off <<= 1) {
        int u = (t >= off) ? s_[t - off] : 0;
        __syncthreads();
        s_[t] += u;
        __syncthreads();
    }
    if (t < SCAN_NBLK) boff[t] = s_[t] - v;
    if (t == 0) offs[NN] = NE;
}

__global__ __launch_bounds__(1024) void scan_apply_kernel(const int* __restrict__ deg,
                                                          const int* __restrict__ boff,
                                                          int* __restrict__ offs,
                                                          int* __restrict__ cursor,
                                                          float* __restrict__ inv_deg) {
    const int i = blockIdx.x * 1024 + threadIdx.x;
    const int lane = threadIdx.x & 63, wid = threadIdx.x >> 6;
    int v = (i < NN) ? deg[i] : 0;
    int x = v;
    #pragma unroll
    for (int off = 1; off < 64; off <<= 1) {
        int y = __shfl_up(x, off);
        if (lane >= off) x += y;
    }
    __shared__ int wsum[16];
    __shared__ int woff[16];
    if (lane == 63) wsum[wid] = x;
    __syncthreads();
    if (threadIdx.x < 16) {
        const int own = wsum[threadIdx.x];
        int s = own;
        #pragma unroll
        for (int off = 1; off < 16; off <<= 1) {
            int y = __shfl_up(s, off, 16);
            if (threadIdx.x >= off) s += y;
        }
        woff[threadIdx.x] = s - own;
    }
    __syncthreads();
    if (i < NN) {
        const int ex = (x - v) + woff[wid] + boff[blockIdx.x];
        offs[i] = ex;
        cursor[i] = ex;
        inv_deg[i] = 1.0f / fmaxf((float)v, 1.0f);
    }
}

__global__ __launch_bounds__(256) void fill_csr_kernel(const int* __restrict__ src,
                                                       const int* __restrict__ tgt,
                                                       int* __restrict__ cursor,
                                                       int* __restrict__ csr) {
    const int e = blockIdx.x * 256 + threadIdx.x;
    if (e < NE) {
        const int pos = atomicAdd(&cursor[tgt[e]], 1);
        __builtin_nontemporal_store(src[e], &csr[pos]);
    }
}

// ================= gather: aggb[n] = bf16( inv_deg[n] * sum h8[src] ) =================
// one 64-lane wave per node; each lane owns 2 fp8 columns; 16-deep unroll
__global__ __launch_bounds__(256) void gather_kernel(const uchar* __restrict__ h8,
                                                     const int* __restrict__ csr,
                                                     const int* __restrict__ offs,
                                                     const float* __restrict__ inv_deg,
                                                     ushort* __restrict__ aggb) {
    const int node = blockIdx.x * 4 + (threadIdx.x >> 6);
    const int lane = threadIdx.x & 63;
    if (node >= NN) return;
    const int beg = offs[node];
    const int end = offs[node + 1];
    const ushort* hp = (const ushort*)h8;   // 2 fp8 per ushort, 64 per row
    float ax = 0.0f, ay = 0.0f;
    int j = beg;
    for (; j + 16 <= end; j += 16) {
        uint uu[16];
        #pragma unroll
        for (int i = 0; i < 16; ++i)
            uu[i] = hp[(size_t)csr[j + i] * 64 + lane];
        #pragma unroll
        for (int i = 0; i < 16; ++i) {
            float x, y;
            fp8pair(uu[i], x, y);
            ax += x; ay += y;
        }
    }
    for (; j + 4 <= end; j += 4) {
        uint uu[4];
        #pragma unroll
        for (int i = 0; i < 4; ++i)
            uu[i] = hp[(size_t)csr[j + i] * 64 + lane];
        #pragma unroll
        for (int i = 0; i < 4; ++i) {
            float x, y;
            fp8pair(uu[i], x, y);
            ax += x; ay += y;
        }
    }
    for (; j < end; ++j) {
        float x, y;
        fp8pair(hp[(size_t)csr[j] * 64 + lane], x, y);
        ax += x; ay += y;
    }
    const float id = inv_deg[node];
    const uint lo = f2bf(ax * id);
    const uint hi = f2bf(ay * id);
    ((uint*)aggb)[(size_t)node * 64 + lane] = lo | (hi << 16);
}

// ================= fused layer (MFMA): h = LN(h + gelu([agg|h] @ [Wl;Wr] + bl)) =================
__global__ __launch_bounds__(256) void layer_mfma(
    float* __restrict__ h, ushort* __restrict__ hb,
    uchar* __restrict__ h8,
    const ushort* __restrict__ aggb, const ushort* __restrict__ Wp,
    const float* __restrict__ bl,
    const float* __restrict__ g, const float* __restrict__ b)
{
    const int t = threadIdx.x;
    const int w = t >> 6, l = t & 63;
    const int gq = l >> 4, li = l & 15;
    const int node0 = blockIdx.x * 64;
    const int ar = min(node0 + w * 16 + li, NN - 1);

    f32x4 acc[8];
    #pragma unroll
    for (int c = 0; c < 8; ++c) acc[c] = (f32x4){0.f, 0.f, 0.f, 0.f};

    const short8* Bp = (const short8*)Wp;
    const short8* Ag = (const short8*)aggb;
    const short8* Hg = (const short8*)hb;
    #pragma unroll
    for (int kk = 0; kk < 8; ++kk) {
        const short8 a = (kk < 4) ? Ag[(size_t)ar * 16 + kk * 4 + gq]
                                  : Hg[(size_t)ar * 16 + (kk - 4) * 4 + gq];
        #pragma unroll
        for (int c = 0; c < 8; ++c) {
            const short8 bf = Bp[(kk * 8 + c) * 64 + l];
            acc[c] = __builtin_amdgcn_mfma_f32_16x16x32_bf16(a, bf, acc[c], 0, 0, 0);
        }
    }

    float bias[8], gam[8], bet[8];
    #pragma unroll
    for (int c = 0; c < 8; ++c) {
        bias[c] = bl[c * 16 + li];
        gam[c]  = g[c * 16 + li];
        bet[c]  = b[c * 16 + li];
    }
    float s[4] = {0, 0, 0, 0}, q[4] = {0, 0, 0, 0};
    #pragma unroll
    for (int r = 0; r < 4; ++r) {
        const int nd = min(node0 + w * 16 + gq * 4 + r, NN - 1);
        #pragma unroll
        for (int c = 0; c < 8; ++c) {
            const float hv = h[(size_t)nd * 128 + c * 16 + li];
            const float tv = hv + gelu_exact(acc[c][r] + bias[c]);
            acc[c][r] = tv;
            s[r] += tv;
            q[r] += tv * tv;
        }
    }
    #pragma unroll
    for (int off = 1; off < 16; off <<= 1)
        #pragma unroll
        for (int r = 0; r < 4; ++r) {
            s[r] += __shfl_xor(s[r], off);
            q[r] += __shfl_xor(q[r], off);
        }
    #pragma unroll
    for (int r = 0; r < 4; ++r) {
        const int node = node0 + w * 16 + gq * 4 + r;
        if (node >= NN) continue;
        const float mean = s[r] * (1.0f / HID);
        const float var  = q[r] * (1.0f / HID) - mean * mean;
        const float rstd = rsqrtf(var + LN_EPS);
        #pragma unroll
        for (int c = 0; c < 8; ++c) {
            const float y = (acc[c][r] - mean) * rstd * gam[c] + bet[c];
            h[(size_t)node * 128 + c * 16 + li] = y;
            hb[(size_t)node * 128 + c * 16 + li] = f2bf(y);
            h8[(size_t)node * 128 + c * 16 + li] = f2fp8(y);
        }
    }
}

extern "C" void kernel_launch(void* const* d_in, const int* in_sizes, int n_in,
                              void* d_out, int out_size, void* d_ws, size_t ws_size,
                              hipStream_t stream) {
    const float* node_feat = (const float*)d_in[0];
    const float* topo      = (const float*)d_in[1];
    const float* embed     = (const float*)d_in[2];
    const float* W_in      = (const float*)d_in[3];
    const float* b_in      = (const float*)d_in[4];
    const float* ln0_g     = (const float*)d_in[5];
    const float* ln0_b     = (const float*)d_in[6];
    const float* Wl        = (const float*)d_in[7];
    const float* bl        = (const float*)d_in[8];
    const float* Wr        = (const float*)d_in[9];
    const float* ln_g      = (const float*)d_in[10];
    const float* ln_b      = (const float*)d_in[11];
    const int*   opcode    = (const int*)d_in[12];
    const int*   edge      = (const int*)d_in[13];
    const int*   e_src = edge;
    const int*   e_tgt = edge + NE;

    float* h = (float*)d_out;   // 100000 x 128 f32

    char* w = (char*)d_ws;
    ushort* hb     = (ushort*)w;  w += (size_t)NN * HID * sizeof(ushort);   // 25.6 MB
    ushort* aggb   = (ushort*)w;  w += (size_t)NN * HID * sizeof(ushort);   // 25.6 MB
    uchar*  h8     = (uchar*)w;   w += (size_t)NN * HID * sizeof(uchar);    // 12.8 MB
    float* inv_deg = (float*)w;   w += 400016;
    int*   deg_i   = (int*)w;     w += 400016;
    int*   offs    = (int*)w;     w += 400016;    // NN+1 ints
    int*   cursor  = (int*)w;     w += 400016;
    int*   bsum    = (int*)w;     w += 1024;
    int*   boff    = (int*)w;     w += 1024;
    int*   csr     = (int*)w;     w += (size_t)NE * sizeof(int);            // 6.4 MB
    ushort* winp   = (ushort*)w;  w += 7 * 8 * 64 * 8 * sizeof(ushort);     // 57 KB
    ushort* wcat   = (ushort*)w;  w += 4 * 8 * 8 * 64 * 8 * sizeof(ushort); // 262 KB

    pack_weights_kernel<<<78, 256, 0, stream>>>(W_in, Wl, Wr, winp, wcat);

    input_proj_mfma<<<(NN + 63) / 64, 256, 0, stream>>>(
        node_feat, topo, embed, opcode, winp, b_in, ln0_g, ln0_b, h, hb, h8);

    hipMemsetAsync(deg_i, 0, (size_t)NN * sizeof(int), stream);
    degree_int_kernel<<<(NE + 255) / 256, 256, 0, stream>>>(e_tgt, deg_i);
    deg_reduce_kernel<<<SCAN_NBLK, 1024, 0, stream>>>(deg_i, bsum);
    bsum_scan_kernel<<<1, 128, 0, stream>>>(bsum, boff, offs);
    scan_apply_kernel<<<SCAN_NBLK, 1024, 0, stream>>>(deg_i, boff, offs, cursor, inv_deg);
    fill_csr_kernel<<<(NE + 255) / 256, 256, 0, stream>>>(e_src, e_tgt, cursor, csr);

    for (int layer = 0; layer < 4; ++layer) {
        gather_kernel<<<NN / 4, 256, 0, stream>>>(h8, csr, offs, inv_deg, aggb);
        layer_mfma<<<(NN + 63) / 64, 256, 0, stream>>>(
            h, hb, h8, aggb, wcat + (size_t)layer * 8 * 8 * 64 * 8,
            bl + (size_t)layer * HID,
            ln_g + (size_t)layer * HID, ln_b + (size_t)layer * HID);
    }
}

// Round 7
// 651.188 us; speedup vs baseline: 1.1932x; 1.1932x over previous
//
#include <hip/hip_runtime.h>
#include <cstdint>
#include <cstddef>

#define NN 100000
#define NE 1600000
#define FEAT 140
#define EMB 64
#define HID 128
#define LN_EPS 1e-5f
#define SCAN_NBLK 98    // ceil(NN/1024)
#define BK_SHIFT 9      // 512 nodes per bucket
#define NBUCK 196       // ceil(100000/512)
#define MAXSEG 20480    // LDS staging entries per bucket (avg 8192, 2.5x margin)

typedef unsigned int uint;
typedef unsigned short ushort;
using short8 = __attribute__((ext_vector_type(8))) short;
using f32x4  = __attribute__((ext_vector_type(4))) float;

__device__ __forceinline__ float gelu_exact(float x) {
    return 0.5f * x * (1.0f + erff(x * 0.70710678118654752440f));
}

__device__ __forceinline__ ushort f2bf(float f) {
    uint u = __float_as_uint(f);
    uint r = (u + 0x7fff + ((u >> 16) & 1)) >> 16;
    return (ushort)r;
}

__device__ __forceinline__ float bf2f(ushort u) {
    return __uint_as_float(((uint)u) << 16);
}

__device__ __forceinline__ float bflo(uint u) {
    return __uint_as_float(u << 16);
}
__device__ __forceinline__ float bfhi(uint u) {
    return __uint_as_float(u & 0xffff0000u);
}

// ================= weight packing into MFMA B-fragment order =================
__global__ __launch_bounds__(256) void pack_weights_kernel(
    const float* __restrict__ W_in, const float* __restrict__ Wl,
    const float* __restrict__ Wr,
    ushort* __restrict__ winp, ushort* __restrict__ wcat)
{
    const int tid = blockIdx.x * 256 + threadIdx.x;
    const int NIN = 7 * 8 * 64;        // 3584
    const int NL  = 8 * 8 * 64;        // 4096
    if (tid < NIN) {
        const int kk = tid >> 9;
        const int c  = (tid >> 6) & 7;
        const int l  = tid & 63;
        const int kbase = kk * 32 + (l >> 4) * 8;
        const int col = c * 16 + (l & 15);
        short8 v;
        #pragma unroll
        for (int j = 0; j < 8; ++j) {
            const int k = kbase + j;
            v[j] = (k < 205) ? (short)f2bf(W_in[k * 128 + col]) : (short)0;
        }
        *(short8*)(winp + (size_t)tid * 8) = v;
    } else if (tid < NIN + 4 * NL) {
        const int t2 = tid - NIN;
        const int layer = t2 >> 12;
        const int r = t2 & (NL - 1);
        const int kk = r >> 9;
        const int c  = (r >> 6) & 7;
        const int l  = r & 63;
        const int kbase = kk * 32 + (l >> 4) * 8;
        const int col = c * 16 + (l & 15);
        short8 v;
        #pragma unroll
        for (int j = 0; j < 8; ++j) {
            const int k = kbase + j;
            const float x = (k < 128)
                ? Wl[(size_t)layer * 16384 + k * 128 + col]
                : Wr[(size_t)layer * 16384 + (k - 128) * 128 + col];
            v[j] = (short)f2bf(x);
        }
        *(short8*)(wcat + (size_t)t2 * 8) = v;
    }
}

// ================= input projection (MFMA) =================
__global__ __launch_bounds__(256) void input_proj_mfma(
    const float* __restrict__ nf, const float* __restrict__ topo,
    const float* __restrict__ embed, const int* __restrict__ opcode,
    const ushort* __restrict__ Wp, const float* __restrict__ b_in,
    const float* __restrict__ g0, const float* __restrict__ b0,
    float* __restrict__ h_out, ushort* __restrict__ hb_out)
{
    __shared__ ushort xs[64 * 232];
    const int t = threadIdx.x;
    const int node0 = blockIdx.x * 64;

    for (int idx = t; idx < 64 * 35; idx += 256) {
        const int row = idx / 35, c = idx - row * 35;
        const int node = min(node0 + row, NN - 1);
        const float4 v = ((const float4*)nf)[(size_t)node * 35 + c];
        ushort* p = &xs[row * 232 + c * 4];
        p[0] = f2bf(v.x); p[1] = f2bf(v.y); p[2] = f2bf(v.z); p[3] = f2bf(v.w);
    }
    for (int idx = t; idx < 64 * 16; idx += 256) {
        const int row = idx >> 4, c = idx & 15;
        const int node = min(node0 + row, NN - 1);
        int op = opcode[node];
        op = min(max(op, 0), 127);
        const float4 v = ((const float4*)embed)[op * 16 + c];
        ushort* p = &xs[row * 232 + 140 + c * 4];
        p[0] = f2bf(v.x); p[1] = f2bf(v.y); p[2] = f2bf(v.z); p[3] = f2bf(v.w);
    }
    if (t < 64) {
        const int node = min(node0 + t, NN - 1);
        xs[t * 232 + 204] = f2bf(topo[node]);
    }
    for (int idx = t; idx < 64 * 19; idx += 256) {
        const int row = idx / 19, c = 205 + (idx - row * 19);
        xs[row * 232 + c] = 0;
    }
    __syncthreads();

    const int w = t >> 6, l = t & 63;
    const int gq = l >> 4, li = l & 15;

    f32x4 acc[8];
    #pragma unroll
    for (int c = 0; c < 8; ++c) acc[c] = (f32x4){0.f, 0.f, 0.f, 0.f};

    const short8* Bp = (const short8*)Wp;
    for (int kk = 0; kk < 7; ++kk) {
        const short8 a = *(const short8*)&xs[(w * 16 + li) * 232 + kk * 32 + gq * 8];
        #pragma unroll
        for (int c = 0; c < 8; ++c) {
            const short8 b = Bp[(kk * 8 + c) * 64 + l];
            acc[c] = __builtin_amdgcn_mfma_f32_16x16x32_bf16(a, b, acc[c], 0, 0, 0);
        }
    }

    float bias[8], gam[8], bet[8];
    #pragma unroll
    for (int c = 0; c < 8; ++c) {
        bias[c] = b_in[c * 16 + li];
        gam[c]  = g0[c * 16 + li];
        bet[c]  = b0[c * 16 + li];
    }
    float s[4] = {0, 0, 0, 0}, q[4] = {0, 0, 0, 0};
    #pragma unroll
    for (int c = 0; c < 8; ++c)
        #pragma unroll
        for (int r = 0; r < 4; ++r) {
            const float u = acc[c][r] + bias[c];
            acc[c][r] = u;
            s[r] += u;
            q[r] += u * u;
        }
    #pragma unroll
    for (int off = 1; off < 16; off <<= 1)
        #pragma unroll
        for (int r = 0; r < 4; ++r) {
            s[r] += __shfl_xor(s[r], off);
            q[r] += __shfl_xor(q[r], off);
        }
    #pragma unroll
    for (int r = 0; r < 4; ++r) {
        const int node = node0 + w * 16 + gq * 4 + r;
        if (node >= NN) continue;
        const float mean = s[r] * (1.0f / HID);
        const float var  = q[r] * (1.0f / HID) - mean * mean;
        const float rstd = rsqrtf(var + LN_EPS);
        #pragma unroll
        for (int c = 0; c < 8; ++c) {
            const float y = gelu_exact((acc[c][r] - mean) * rstd * gam[c] + bet[c]);
            h_out[(size_t)node * 128 + c * 16 + li] = y;
            hb_out[(size_t)node * 128 + c * 16 + li] = f2bf(y);
        }
    }
}

// ================= CSR build (bucketed, coalesced) =================
// Pass A: per-node degree atomics + per-bucket histogram
__global__ __launch_bounds__(256) void degree_hist_kernel(const int* __restrict__ tgt,
                                                          int* __restrict__ deg,
                                                          int* __restrict__ bhist) {
    __shared__ int lh[NBUCK];
    for (int i = threadIdx.x; i < NBUCK; i += 256) lh[i] = 0;
    __syncthreads();
    const int e0 = blockIdx.x * 2048;
    const int eend = min(e0 + 2048, NE);
    for (int e = e0 + threadIdx.x; e < eend; e += 256) {
        const int tv = tgt[e];
        atomicAdd(&deg[tv], 1);
        atomicAdd(&lh[tv >> BK_SHIFT], 1);
    }
    __syncthreads();
    for (int i = threadIdx.x; i < NBUCK; i += 256)
        if (lh[i]) atomicAdd(&bhist[i], lh[i]);
}

// scan of NBUCK bucket counts (one block)
__global__ __launch_bounds__(256) void bucket_scan_kernel(const int* __restrict__ bhist,
                                                          int* __restrict__ bpos,
                                                          int* __restrict__ bcur) {
    __shared__ int s_[256];
    const int t = threadIdx.x;
    int v = (t < NBUCK) ? bhist[t] : 0;
    s_[t] = v;
    __syncthreads();
    for (int off = 1; off < 256; off <<= 1) {
        int u = (t >= off) ? s_[t - off] : 0;
        __syncthreads();
        s_[t] += u;
        __syncthreads();
    }
    if (t < NBUCK) { bpos[t] = s_[t] - v; bcur[t] = s_[t] - v; }
}

// Pass B: partition edges into bucket-grouped (tgt,src) pairs; block-private chunks
__global__ __launch_bounds__(256) void partition_kernel(const int* __restrict__ src,
                                                        const int* __restrict__ tgt,
                                                        int* __restrict__ bcur,
                                                        uint2* __restrict__ pairs) {
    __shared__ int lh[NBUCK];
    __shared__ int gbase[NBUCK];
    for (int i = threadIdx.x; i < NBUCK; i += 256) lh[i] = 0;
    __syncthreads();
    const int e0 = blockIdx.x * 2048;
    const int eend = min(e0 + 2048, NE);
    int myb[8], myr[8], mys[8], myt[8];
    int cnt = 0;
    for (int e = e0 + threadIdx.x; e < eend; e += 256) {
        const int tv = tgt[e];
        const int b = tv >> BK_SHIFT;
        myb[cnt] = b; myt[cnt] = tv; mys[cnt] = src[e];
        myr[cnt] = atomicAdd(&lh[b], 1);
        ++cnt;
    }
    __syncthreads();
    for (int i = threadIdx.x; i < NBUCK; i += 256)
        gbase[i] = lh[i] ? atomicAdd(&bcur[i], lh[i]) : 0;
    __syncthreads();
    for (int i = 0; i < cnt; ++i)
        pairs[gbase[myb[i]] + myr[i]] = make_uint2((uint)myt[i], (uint)mys[i]);
}

// Pass C: one block per bucket; fill csr segment in LDS, flush coalesced
__global__ __launch_bounds__(256) void bucket_fill_kernel(const uint2* __restrict__ pairs,
                                                          const int* __restrict__ bpos,
                                                          const int* __restrict__ bhist,
                                                          const int* __restrict__ offs,
                                                          int* __restrict__ csr) {
    __shared__ int loffs[513];
    __shared__ int lcur[512];
    __shared__ int stage[MAXSEG];
    const int b = blockIdx.x;
    const int n0 = b << BK_SHIFT;
    const int nend = min(n0 + 512, NN);
    const int nn = nend - n0;
    for (int i = threadIdx.x; i <= nn; i += 256) loffs[i] = offs[n0 + i];
    for (int i = threadIdx.x; i < nn; i += 256) lcur[i] = 0;
    __syncthreads();
    const int base0 = loffs[0];
    const int seglen = loffs[nn] - base0;
    const int p0 = bpos[b], pc = bhist[b];
    if (seglen <= MAXSEG) {
        for (int i = threadIdx.x; i < pc; i += 256) {
            const uint2 pr = pairs[p0 + i];
            const int ln = (int)pr.x - n0;
            const int p = atomicAdd(&lcur[ln], 1);
            stage[loffs[ln] - base0 + p] = (int)pr.y;
        }
        __syncthreads();
        for (int i = threadIdx.x; i < seglen; i += 256) csr[base0 + i] = stage[i];
    } else {
        // fallback (never expected for this graph): direct global fill
        for (int i = threadIdx.x; i < pc; i += 256) {
            const uint2 pr = pairs[p0 + i];
            const int ln = (int)pr.x - n0;
            const int p = atomicAdd(&lcur[ln], 1);
            csr[loffs[ln] + p] = (int)pr.y;
        }
    }
}

// per-node offsets: reduce / scan / apply (unchanged from R5)
__global__ __launch_bounds__(1024) void deg_reduce_kernel(const int* __restrict__ deg,
                                                          int* __restrict__ bsum) {
    const int i = blockIdx.x * 1024 + threadIdx.x;
    int v = (i < NN) ? deg[i] : 0;
    #pragma unroll
    for (int off = 32; off >= 1; off >>= 1) v += __shfl_down(v, off);
    __shared__ int wsum[16];
    const int lane = threadIdx.x & 63, wid = threadIdx.x >> 6;
    if (lane == 0) wsum[wid] = v;
    __syncthreads();
    if (threadIdx.x < 16) {
        int s = wsum[threadIdx.x];
        #pragma unroll
        for (int off = 8; off >= 1; off >>= 1) s += __shfl_down(s, off, 16);
        if (threadIdx.x == 0) bsum[blockIdx.x] = s;
    }
}

__global__ __launch_bounds__(128) void bsum_scan_kernel(const int* __restrict__ bsum,
                                                        int* __restrict__ boff,
                                                        int* __restrict__ offs) {
    __shared__ int s_[128];
    const int t = threadIdx.x;
    int v = (t < SCAN_NBLK) ? bsum[t] : 0;
    s_[t] = v;
    __syncthreads();
    for (int off = 1; off < 128; off <<= 1) {
        int u = (t >= off) ? s_[t - off] : 0;
        __syncthreads();
        s_[t] += u;
        __syncthreads();
    }
    if (t < SCAN_NBLK) boff[t] = s_[t] - v;
    if (t == 0) offs[NN] = NE;
}

__global__ __launch_bounds__(1024) void scan_apply_kernel(const int* __restrict__ deg,
                                                          const int* __restrict__ boff,
                                                          int* __restrict__ offs,
                                                          float* __restrict__ inv_deg) {
    const int i = blockIdx.x * 1024 + threadIdx.x;
    const int lane = threadIdx.x & 63, wid = threadIdx.x >> 6;
    int v = (i < NN) ? deg[i] : 0;
    int x = v;
    #pragma unroll
    for (int off = 1; off < 64; off <<= 1) {
        int y = __shfl_up(x, off);
        if (lane >= off) x += y;
    }
    __shared__ int wsum[16];
    __shared__ int woff[16];
    if (lane == 63) wsum[wid] = x;
    __syncthreads();
    if (threadIdx.x < 16) {
        const int own = wsum[threadIdx.x];
        int s = own;
        #pragma unroll
        for (int off = 1; off < 16; off <<= 1) {
            int y = __shfl_up(s, off, 16);
            if (threadIdx.x >= off) s += y;
        }
        woff[threadIdx.x] = s - own;
    }
    __syncthreads();
    if (i < NN) {
        const int ex = (x - v) + woff[wid] + boff[blockIdx.x];
        offs[i] = ex;
        inv_deg[i] = 1.0f / fmaxf((float)v, 1.0f);
    }
}

// ================= gather: aggb[n] = bf16( inv_deg[n] * sum hb[src] ) =================
__global__ __launch_bounds__(256) void gather_kernel(const ushort* __restrict__ hb,
                                                     const int* __restrict__ csr,
                                                     const int* __restrict__ offs,
                                                     const float* __restrict__ inv_deg,
                                                     ushort* __restrict__ aggb) {
    const int node = blockIdx.x * 4 + (threadIdx.x >> 6);
    const int lane = threadIdx.x & 63;
    if (node >= NN) return;
    const int beg = offs[node];
    const int end = offs[node + 1];
    const uint* hp = (const uint*)hb;
    float ax = 0.0f, ay = 0.0f;
    int j = beg;
    for (; j + 8 <= end; j += 8) {
        int s0 = csr[j + 0], s1 = csr[j + 1], s2 = csr[j + 2], s3 = csr[j + 3];
        int s4 = csr[j + 4], s5 = csr[j + 5], s6 = csr[j + 6], s7 = csr[j + 7];
        uint u0 = hp[(size_t)s0 * 64 + lane];
        uint u1 = hp[(size_t)s1 * 64 + lane];
        uint u2 = hp[(size_t)s2 * 64 + lane];
        uint u3 = hp[(size_t)s3 * 64 + lane];
        uint u4 = hp[(size_t)s4 * 64 + lane];
        uint u5 = hp[(size_t)s5 * 64 + lane];
        uint u6 = hp[(size_t)s6 * 64 + lane];
        uint u7 = hp[(size_t)s7 * 64 + lane];
        float ax0 = bflo(u0) + bflo(u1);
        float ax1 = bflo(u2) + bflo(u3);
        float ax2 = bflo(u4) + bflo(u5);
        float ax3 = bflo(u6) + bflo(u7);
        float ay0 = bfhi(u0) + bfhi(u1);
        float ay1 = bfhi(u2) + bfhi(u3);
        float ay2 = bfhi(u4) + bfhi(u5);
        float ay3 = bfhi(u6) + bfhi(u7);
        ax += (ax0 + ax1) + (ax2 + ax3);
        ay += (ay0 + ay1) + (ay2 + ay3);
    }
    for (; j + 2 <= end; j += 2) {
        int s0 = csr[j + 0], s1 = csr[j + 1];
        uint u0 = hp[(size_t)s0 * 64 + lane];
        uint u1 = hp[(size_t)s1 * 64 + lane];
        ax += bflo(u0) + bflo(u1);
        ay += bfhi(u0) + bfhi(u1);
    }
    if (j < end) {
        uint u0 = hp[(size_t)csr[j] * 64 + lane];
        ax += bflo(u0);
        ay += bfhi(u0);
    }
    const float id = inv_deg[node];
    const uint lo = f2bf(ax * id);
    const uint hi = f2bf(ay * id);
    ((uint*)aggb)[(size_t)node * 64 + lane] = lo | (hi << 16);
}

// ================= fused layer (MFMA): h = LN(h + gelu([agg|h] @ [Wl;Wr] + bl)) =================
__global__ __launch_bounds__(256) void layer_mfma(
    float* __restrict__ h, ushort* __restrict__ hb,
    const ushort* __restrict__ aggb, const ushort* __restrict__ Wp,
    const float* __restrict__ bl,
    const float* __restrict__ g, const float* __restrict__ b)
{
    const int t = threadIdx.x;
    const int w = t >> 6, l = t & 63;
    const int gq = l >> 4, li = l & 15;
    const int node0 = blockIdx.x * 64;
    const int ar = min(node0 + w * 16 + li, NN - 1);

    f32x4 acc[8];
    #pragma unroll
    for (int c = 0; c < 8; ++c) acc[c] = (f32x4){0.f, 0.f, 0.f, 0.f};

    const short8* Bp = (const short8*)Wp;
    const short8* Ag = (const short8*)aggb;
    const short8* Hg = (const short8*)hb;
    #pragma unroll
    for (int kk = 0; kk < 8; ++kk) {
        const short8 a = (kk < 4) ? Ag[(size_t)ar * 16 + kk * 4 + gq]
                                  : Hg[(size_t)ar * 16 + (kk - 4) * 4 + gq];
        #pragma unroll
        for (int c = 0; c < 8; ++c) {
            const short8 bf = Bp[(kk * 8 + c) * 64 + l];
            acc[c] = __builtin_amdgcn_mfma_f32_16x16x32_bf16(a, bf, acc[c], 0, 0, 0);
        }
    }

    float bias[8], gam[8], bet[8];
    #pragma unroll
    for (int c = 0; c < 8; ++c) {
        bias[c] = bl[c * 16 + li];
        gam[c]  = g[c * 16 + li];
        bet[c]  = b[c * 16 + li];
    }
    float s[4] = {0, 0, 0, 0}, q[4] = {0, 0, 0, 0};
    #pragma unroll
    for (int r = 0; r < 4; ++r) {
        const int nd = min(node0 + w * 16 + gq * 4 + r, NN - 1);
        #pragma unroll
        for (int c = 0; c < 8; ++c) {
            const float hv = h[(size_t)nd * 128 + c * 16 + li];
            const float tv = hv + gelu_exact(acc[c][r] + bias[c]);
            acc[c][r] = tv;
            s[r] += tv;
            q[r] += tv * tv;
        }
    }
    #pragma unroll
    for (int off = 1; off < 16; off <<= 1)
        #pragma unroll
        for (int r = 0; r < 4; ++r) {
            s[r] += __shfl_xor(s[r], off);
            q[r] += __shfl_xor(q[r], off);
        }
    #pragma unroll
    for (int r = 0; r < 4; ++r) {
        const int node = node0 + w * 16 + gq * 4 + r;
        if (node >= NN) continue;
        const float mean = s[r] * (1.0f / HID);
        const float var  = q[r] * (1.0f / HID) - mean * mean;
        const float rstd = rsqrtf(var + LN_EPS);
        #pragma unroll
        for (int c = 0; c < 8; ++c) {
            const float y = (acc[c][r] - mean) * rstd * gam[c] + bet[c];
            h[(size_t)node * 128 + c * 16 + li] = y;
            hb[(size_t)node * 128 + c * 16 + li] = f2bf(y);
        }
    }
}

extern "C" void kernel_launch(void* const* d_in, const int* in_sizes, int n_in,
                              void* d_out, int out_size, void* d_ws, size_t ws_size,
                              hipStream_t stream) {
    const float* node_feat = (const float*)d_in[0];
    const float* topo      = (const float*)d_in[1];
    const float* embed     = (const float*)d_in[2];
    const float* W_in      = (const float*)d_in[3];
    const float* b_in      = (const float*)d_in[4];
    const float* ln0_g     = (const float*)d_in[5];
    const float* ln0_b     = (const float*)d_in[6];
    const float* Wl        = (const float*)d_in[7];
    const float* bl        = (const float*)d_in[8];
    const float* Wr        = (const float*)d_in[9];
    const float* ln_g      = (const float*)d_in[10];
    const float* ln_b      = (const float*)d_in[11];
    const int*   opcode    = (const int*)d_in[12];
    const int*   edge      = (const int*)d_in[13];
    const int*   e_src = edge;
    const int*   e_tgt = edge + NE;

    float* h = (float*)d_out;   // 100000 x 128 f32

    char* w = (char*)d_ws;
    ushort* hb     = (ushort*)w;  w += (size_t)NN * HID * sizeof(ushort);   // 25.6 MB
    ushort* aggb   = (ushort*)w;  w += (size_t)NN * HID * sizeof(ushort);   // 25.6 MB
    float* inv_deg = (float*)w;   w += 400016;
    int*   deg_i   = (int*)w;     w += 400016;
    int*   offs    = (int*)w;     w += 400016;    // NN+1 ints
    int*   bsum    = (int*)w;     w += 1024;
    int*   boff    = (int*)w;     w += 1024;
    int*   bhist   = (int*)w;     w += 1024;
    int*   bpos    = (int*)w;     w += 1024;
    int*   bcur    = (int*)w;     w += 1024;
    int*   csr     = (int*)w;     w += (size_t)NE * sizeof(int);            // 6.4 MB
    uint2* pairs   = (uint2*)w;   w += (size_t)NE * sizeof(uint2);          // 12.8 MB
    ushort* winp   = (ushort*)w;  w += 7 * 8 * 64 * 8 * sizeof(ushort);     // 57 KB
    ushort* wcat   = (ushort*)w;  w += 4 * 8 * 8 * 64 * 8 * sizeof(ushort); // 262 KB

    const int EBLK = (NE + 2047) / 2048;   // 782

    pack_weights_kernel<<<78, 256, 0, stream>>>(W_in, Wl, Wr, winp, wcat);

    input_proj_mfma<<<(NN + 63) / 64, 256, 0, stream>>>(
        node_feat, topo, embed, opcode, winp, b_in, ln0_g, ln0_b, h, hb);

    // CSR build (bucketed)
    hipMemsetAsync(deg_i, 0, (size_t)NN * sizeof(int), stream);
    hipMemsetAsync(bhist, 0, NBUCK * sizeof(int), stream);
    degree_hist_kernel<<<EBLK, 256, 0, stream>>>(e_tgt, deg_i, bhist);
    bucket_scan_kernel<<<1, 256, 0, stream>>>(bhist, bpos, bcur);
    deg_reduce_kernel<<<SCAN_NBLK, 1024, 0, stream>>>(deg_i, bsum);
    bsum_scan_kernel<<<1, 128, 0, stream>>>(bsum, boff, offs);
    scan_apply_kernel<<<SCAN_NBLK, 1024, 0, stream>>>(deg_i, boff, offs, inv_deg);
    partition_kernel<<<EBLK, 256, 0, stream>>>(e_src, e_tgt, bcur, pairs);
    bucket_fill_kernel<<<NBUCK, 256, 0, stream>>>(pairs, bpos, bhist, offs, csr);

    for (int layer = 0; layer < 4; ++layer) {
        gather_kernel<<<NN / 4, 256, 0, stream>>>(hb, csr, offs, inv_deg, aggb);
        layer_mfma<<<(NN + 63) / 64, 256, 0, stream>>>(
            h, hb, aggb, wcat + (size_t)layer * 8 * 8 * 64 * 8,
            bl + (size_t)layer * HID,
            ln_g + (size_t)layer * HID, ln_b + (size_t)layer * HID);
    }
}

// Round 8
// 576.352 us; speedup vs baseline: 1.3481x; 1.1298x over previous
//
#include <hip/hip_runtime.h>
#include <cstdint>
#include <cstddef>

#define NN 100000
#define NE 1600000
#define FEAT 140
#define EMB 64
#define HID 128
#define LN_EPS 1e-5f
#define BK_SHIFT 9      // 512 nodes per bucket
#define NBUCK 196       // ceil(100000/512)
#define MAXSEG 20480    // LDS staging entries per bucket (avg 8163, 2.5x margin)

typedef unsigned int uint;
typedef unsigned short ushort;
using short8 = __attribute__((ext_vector_type(8))) short;
using f32x4  = __attribute__((ext_vector_type(4))) float;

__device__ __forceinline__ float gelu_exact(float x) {
    return 0.5f * x * (1.0f + erff(x * 0.70710678118654752440f));
}

__device__ __forceinline__ ushort f2bf(float f) {
    uint u = __float_as_uint(f);
    uint r = (u + 0x7fff + ((u >> 16) & 1)) >> 16;
    return (ushort)r;
}

__device__ __forceinline__ float bf2f(ushort u) {
    return __uint_as_float(((uint)u) << 16);
}

__device__ __forceinline__ float bflo(uint u) {
    return __uint_as_float(u << 16);
}
__device__ __forceinline__ float bfhi(uint u) {
    return __uint_as_float(u & 0xffff0000u);
}

// ================= weight packing into MFMA B-fragment order =================
__global__ __launch_bounds__(256) void pack_weights_kernel(
    const float* __restrict__ W_in, const float* __restrict__ Wl,
    const float* __restrict__ Wr,
    ushort* __restrict__ winp, ushort* __restrict__ wcat)
{
    const int tid = blockIdx.x * 256 + threadIdx.x;
    const int NIN = 7 * 8 * 64;        // 3584
    const int NL  = 8 * 8 * 64;        // 4096
    if (tid < NIN) {
        const int kk = tid >> 9;
        const int c  = (tid >> 6) & 7;
        const int l  = tid & 63;
        const int kbase = kk * 32 + (l >> 4) * 8;
        const int col = c * 16 + (l & 15);
        short8 v;
        #pragma unroll
        for (int j = 0; j < 8; ++j) {
            const int k = kbase + j;
            v[j] = (k < 205) ? (short)f2bf(W_in[k * 128 + col]) : (short)0;
        }
        *(short8*)(winp + (size_t)tid * 8) = v;
    } else if (tid < NIN + 4 * NL) {
        const int t2 = tid - NIN;
        const int layer = t2 >> 12;
        const int r = t2 & (NL - 1);
        const int kk = r >> 9;
        const int c  = (r >> 6) & 7;
        const int l  = r & 63;
        const int kbase = kk * 32 + (l >> 4) * 8;
        const int col = c * 16 + (l & 15);
        short8 v;
        #pragma unroll
        for (int j = 0; j < 8; ++j) {
            const int k = kbase + j;
            const float x = (k < 128)
                ? Wl[(size_t)layer * 16384 + k * 128 + col]
                : Wr[(size_t)layer * 16384 + (k - 128) * 128 + col];
            v[j] = (short)f2bf(x);
        }
        *(short8*)(wcat + (size_t)t2 * 8) = v;
    }
}

// ================= input projection (MFMA): hb = bf16(gelu(LN(concat @ W_in + b_in))) =================
__global__ __launch_bounds__(256) void input_proj_mfma(
    const float* __restrict__ nf, const float* __restrict__ topo,
    const float* __restrict__ embed, const int* __restrict__ opcode,
    const ushort* __restrict__ Wp, const float* __restrict__ b_in,
    const float* __restrict__ g0, const float* __restrict__ b0,
    ushort* __restrict__ hb_out)
{
    __shared__ ushort xs[64 * 232];
    const int t = threadIdx.x;
    const int node0 = blockIdx.x * 64;

    for (int idx = t; idx < 64 * 35; idx += 256) {
        const int row = idx / 35, c = idx - row * 35;
        const int node = min(node0 + row, NN - 1);
        const float4 v = ((const float4*)nf)[(size_t)node * 35 + c];
        ushort* p = &xs[row * 232 + c * 4];
        p[0] = f2bf(v.x); p[1] = f2bf(v.y); p[2] = f2bf(v.z); p[3] = f2bf(v.w);
    }
    for (int idx = t; idx < 64 * 16; idx += 256) {
        const int row = idx >> 4, c = idx & 15;
        const int node = min(node0 + row, NN - 1);
        int op = opcode[node];
        op = min(max(op, 0), 127);
        const float4 v = ((const float4*)embed)[op * 16 + c];
        ushort* p = &xs[row * 232 + 140 + c * 4];
        p[0] = f2bf(v.x); p[1] = f2bf(v.y); p[2] = f2bf(v.z); p[3] = f2bf(v.w);
    }
    if (t < 64) {
        const int node = min(node0 + t, NN - 1);
        xs[t * 232 + 204] = f2bf(topo[node]);
    }
    for (int idx = t; idx < 64 * 19; idx += 256) {
        const int row = idx / 19, c = 205 + (idx - row * 19);
        xs[row * 232 + c] = 0;
    }
    __syncthreads();

    const int w = t >> 6, l = t & 63;
    const int gq = l >> 4, li = l & 15;

    f32x4 acc[8];
    #pragma unroll
    for (int c = 0; c < 8; ++c) acc[c] = (f32x4){0.f, 0.f, 0.f, 0.f};

    const short8* Bp = (const short8*)Wp;
    for (int kk = 0; kk < 7; ++kk) {
        const short8 a = *(const short8*)&xs[(w * 16 + li) * 232 + kk * 32 + gq * 8];
        #pragma unroll
        for (int c = 0; c < 8; ++c) {
            const short8 b = Bp[(kk * 8 + c) * 64 + l];
            acc[c] = __builtin_amdgcn_mfma_f32_16x16x32_bf16(a, b, acc[c], 0, 0, 0);
        }
    }

    float bias[8], gam[8], bet[8];
    #pragma unroll
    for (int c = 0; c < 8; ++c) {
        bias[c] = b_in[c * 16 + li];
        gam[c]  = g0[c * 16 + li];
        bet[c]  = b0[c * 16 + li];
    }
    float s[4] = {0, 0, 0, 0}, q[4] = {0, 0, 0, 0};
    #pragma unroll
    for (int c = 0; c < 8; ++c)
        #pragma unroll
        for (int r = 0; r < 4; ++r) {
            const float u = acc[c][r] + bias[c];
            acc[c][r] = u;
            s[r] += u;
            q[r] += u * u;
        }
    #pragma unroll
    for (int off = 1; off < 16; off <<= 1)
        #pragma unroll
        for (int r = 0; r < 4; ++r) {
            s[r] += __shfl_xor(s[r], off);
            q[r] += __shfl_xor(q[r], off);
        }
    #pragma unroll
    for (int r = 0; r < 4; ++r) {
        const int node = node0 + w * 16 + gq * 4 + r;
        if (node >= NN) continue;
        const float mean = s[r] * (1.0f / HID);
        const float var  = q[r] * (1.0f / HID) - mean * mean;
        const float rstd = rsqrtf(var + LN_EPS);
        #pragma unroll
        for (int c = 0; c < 8; ++c) {
            const float y = gelu_exact((acc[c][r] - mean) * rstd * gam[c] + bet[c]);
            hb_out[(size_t)node * 128 + c * 16 + li] = f2bf(y);
        }
    }
}

// ================= CSR build (bucketed, no per-node global atomics) =================
// Pass A: bucket histogram only
__global__ __launch_bounds__(256) void hist_kernel(const int* __restrict__ tgt,
                                                   int* __restrict__ bhist) {
    __shared__ int lh[NBUCK];
    for (int i = threadIdx.x; i < NBUCK; i += 256) lh[i] = 0;
    __syncthreads();
    const int e0 = blockIdx.x * 2048;
    const int eend = min(e0 + 2048, NE);
    for (int e = e0 + threadIdx.x; e < eend; e += 256)
        atomicAdd(&lh[tgt[e] >> BK_SHIFT], 1);
    __syncthreads();
    for (int i = threadIdx.x; i < NBUCK; i += 256)
        if (lh[i]) atomicAdd(&bhist[i], lh[i]);
}

// scan of NBUCK bucket counts (one block)
__global__ __launch_bounds__(256) void bucket_scan_kernel(const int* __restrict__ bhist,
                                                          int* __restrict__ bpos,
                                                          int* __restrict__ bcur) {
    __shared__ int s_[256];
    const int t = threadIdx.x;
    int v = (t < NBUCK) ? bhist[t] : 0;
    s_[t] = v;
    __syncthreads();
    for (int off = 1; off < 256; off <<= 1) {
        int u = (t >= off) ? s_[t - off] : 0;
        __syncthreads();
        s_[t] += u;
        __syncthreads();
    }
    if (t < NBUCK) { bpos[t] = s_[t] - v; bcur[t] = s_[t] - v; }
}

// Pass B: partition edges into bucket-grouped (tgt,src) pairs; block-private chunks
__global__ __launch_bounds__(256) void partition_kernel(const int* __restrict__ src,
                                                        const int* __restrict__ tgt,
                                                        int* __restrict__ bcur,
                                                        uint2* __restrict__ pairs) {
    __shared__ int lh[NBUCK];
    __shared__ int gbase[NBUCK];
    for (int i = threadIdx.x; i < NBUCK; i += 256) lh[i] = 0;
    __syncthreads();
    const int e0 = blockIdx.x * 2048;
    const int eend = min(e0 + 2048, NE);
    int myb[8], myr[8], mys[8], myt[8];
    int cnt = 0;
    for (int e = e0 + threadIdx.x; e < eend; e += 256) {
        const int tv = tgt[e];
        const int b = tv >> BK_SHIFT;
        myb[cnt] = b; myt[cnt] = tv; mys[cnt] = src[e];
        myr[cnt] = atomicAdd(&lh[b], 1);
        ++cnt;
    }
    __syncthreads();
    for (int i = threadIdx.x; i < NBUCK; i += 256)
        gbase[i] = lh[i] ? atomicAdd(&bcur[i], lh[i]) : 0;
    __syncthreads();
    for (int i = 0; i < cnt; ++i)
        pairs[gbase[myb[i]] + myr[i]] = make_uint2((uint)myt[i], (uint)mys[i]);
}

// Pass C: one block per bucket. Computes per-node degrees/offsets in LDS
// (bucket base = bpos[b] == global edge prefix), writes offs/inv_deg coalesced,
// then fills its csr segment via LDS staging and flushes coalesced.
__global__ __launch_bounds__(256) void bucket_fill_kernel(const uint2* __restrict__ pairs,
                                                          const int* __restrict__ bpos,
                                                          const int* __restrict__ bhist,
                                                          int* __restrict__ offs,
                                                          float* __restrict__ inv_deg,
                                                          int* __restrict__ csr) {
    __shared__ int cnt[512];
    __shared__ int pref[512];
    __shared__ int ssum[256];
    __shared__ int stage[MAXSEG];
    const int t = threadIdx.x;
    const int b = blockIdx.x;
    const int n0 = b << BK_SHIFT;
    const int nn = min(512, NN - n0);
    const int p0 = bpos[b], pc = bhist[b];

    for (int i = t; i < 512; i += 256) cnt[i] = 0;
    __syncthreads();
    // count degrees
    for (int i = t; i < pc; i += 256)
        atomicAdd(&cnt[(int)pairs[p0 + i].x - n0], 1);
    __syncthreads();
    // scan 512 counts: thread t owns nodes 2t, 2t+1
    const int a0 = cnt[2 * t], a1 = cnt[2 * t + 1];
    ssum[t] = a0 + a1;
    __syncthreads();
    for (int off = 1; off < 256; off <<= 1) {
        int u = (t >= off) ? ssum[t - off] : 0;
        __syncthreads();
        ssum[t] += u;
        __syncthreads();
    }
    const int ebase = ssum[t] - a0 - a1;   // exclusive over pairs-of-nodes
    pref[2 * t] = ebase;
    pref[2 * t + 1] = ebase + a0;
    __syncthreads();
    // write offs + inv_deg (coalesced)
    for (int i = t; i < nn; i += 256) {
        offs[n0 + i] = p0 + pref[i];
        inv_deg[n0 + i] = 1.0f / fmaxf((float)cnt[i], 1.0f);
    }
    if (b == NBUCK - 1 && t == 0) offs[NN] = NE;
    // reset cnt as cursor
    __syncthreads();
    for (int i = t; i < 512; i += 256) cnt[i] = 0;
    __syncthreads();
    if (pc <= MAXSEG) {
        for (int i = t; i < pc; i += 256) {
            const uint2 pr = pairs[p0 + i];
            const int ln = (int)pr.x - n0;
            const int p = atomicAdd(&cnt[ln], 1);
            stage[pref[ln] + p] = (int)pr.y;
        }
        __syncthreads();
        for (int i = t; i < pc; i += 256) csr[p0 + i] = stage[i];
    } else {
        // fallback (not expected): direct global scatter
        for (int i = t; i < pc; i += 256) {
            const uint2 pr = pairs[p0 + i];
            const int ln = (int)pr.x - n0;
            const int p = atomicAdd(&cnt[ln], 1);
            csr[p0 + pref[ln] + p] = (int)pr.y;
        }
    }
}

// ================= gather: aggb[n] = bf16( inv_deg[n] * sum hb[src] ) =================
__global__ __launch_bounds__(256) void gather_kernel(const ushort* __restrict__ hb,
                                                     const int* __restrict__ csr,
                                                     const int* __restrict__ offs,
                                                     const float* __restrict__ inv_deg,
                                                     ushort* __restrict__ aggb) {
    const int node = blockIdx.x * 4 + (threadIdx.x >> 6);
    const int lane = threadIdx.x & 63;
    if (node >= NN) return;
    const int beg = offs[node];
    const int end = offs[node + 1];
    const uint* hp = (const uint*)hb;
    float ax = 0.0f, ay = 0.0f;
    int j = beg;
    for (; j + 8 <= end; j += 8) {
        int s0 = csr[j + 0], s1 = csr[j + 1], s2 = csr[j + 2], s3 = csr[j + 3];
        int s4 = csr[j + 4], s5 = csr[j + 5], s6 = csr[j + 6], s7 = csr[j + 7];
        uint u0 = hp[(size_t)s0 * 64 + lane];
        uint u1 = hp[(size_t)s1 * 64 + lane];
        uint u2 = hp[(size_t)s2 * 64 + lane];
        uint u3 = hp[(size_t)s3 * 64 + lane];
        uint u4 = hp[(size_t)s4 * 64 + lane];
        uint u5 = hp[(size_t)s5 * 64 + lane];
        uint u6 = hp[(size_t)s6 * 64 + lane];
        uint u7 = hp[(size_t)s7 * 64 + lane];
        float ax0 = bflo(u0) + bflo(u1);
        float ax1 = bflo(u2) + bflo(u3);
        float ax2 = bflo(u4) + bflo(u5);
        float ax3 = bflo(u6) + bflo(u7);
        float ay0 = bfhi(u0) + bfhi(u1);
        float ay1 = bfhi(u2) + bfhi(u3);
        float ay2 = bfhi(u4) + bfhi(u5);
        float ay3 = bfhi(u6) + bfhi(u7);
        ax += (ax0 + ax1) + (ax2 + ax3);
        ay += (ay0 + ay1) + (ay2 + ay3);
    }
    for (; j + 2 <= end; j += 2) {
        int s0 = csr[j + 0], s1 = csr[j + 1];
        uint u0 = hp[(size_t)s0 * 64 + lane];
        uint u1 = hp[(size_t)s1 * 64 + lane];
        ax += bflo(u0) + bflo(u1);
        ay += bfhi(u0) + bfhi(u1);
    }
    if (j < end) {
        uint u0 = hp[(size_t)csr[j] * 64 + lane];
        ax += bflo(u0);
        ay += bfhi(u0);
    }
    const float id = inv_deg[node];
    const uint lo = f2bf(ax * id);
    const uint hi = f2bf(ay * id);
    ((uint*)aggb)[(size_t)node * 64 + lane] = lo | (hi << 16);
}

// ================= fused layer (MFMA): hb = bf16(LN(hb + gelu([agg|hb] @ [Wl;Wr] + bl))) =================
// write_f32 != 0 -> also write f32 result to hout (final layer -> d_out)
__global__ __launch_bounds__(256) void layer_mfma(
    ushort* __restrict__ hb, const ushort* __restrict__ aggb,
    const ushort* __restrict__ Wp, const float* __restrict__ bl,
    const float* __restrict__ g, const float* __restrict__ b,
    float* __restrict__ hout, int write_f32)
{
    const int t = threadIdx.x;
    const int w = t >> 6, l = t & 63;
    const int gq = l >> 4, li = l & 15;
    const int node0 = blockIdx.x * 64;
    const int ar = min(node0 + w * 16 + li, NN - 1);

    f32x4 acc[8];
    #pragma unroll
    for (int c = 0; c < 8; ++c) acc[c] = (f32x4){0.f, 0.f, 0.f, 0.f};

    const short8* Bp = (const short8*)Wp;
    const short8* Ag = (const short8*)aggb;
    const short8* Hg = (const short8*)hb;
    #pragma unroll
    for (int kk = 0; kk < 8; ++kk) {
        const short8 a = (kk < 4) ? Ag[(size_t)ar * 16 + kk * 4 + gq]
                                  : Hg[(size_t)ar * 16 + (kk - 4) * 4 + gq];
        #pragma unroll
        for (int c = 0; c < 8; ++c) {
            const short8 bf = Bp[(kk * 8 + c) * 64 + l];
            acc[c] = __builtin_amdgcn_mfma_f32_16x16x32_bf16(a, bf, acc[c], 0, 0, 0);
        }
    }

    float bias[8], gam[8], bet[8];
    #pragma unroll
    for (int c = 0; c < 8; ++c) {
        bias[c] = bl[c * 16 + li];
        gam[c]  = g[c * 16 + li];
        bet[c]  = b[c * 16 + li];
    }
    float s[4] = {0, 0, 0, 0}, q[4] = {0, 0, 0, 0};
    #pragma unroll
    for (int r = 0; r < 4; ++r) {
        const int nd = min(node0 + w * 16 + gq * 4 + r, NN - 1);
        #pragma unroll
        for (int c = 0; c < 8; ++c) {
            const float hv = bf2f(hb[(size_t)nd * 128 + c * 16 + li]);
            const float tv = hv + gelu_exact(acc[c][r] + bias[c]);
            acc[c][r] = tv;
            s[r] += tv;
            q[r] += tv * tv;
        }
    }
    #pragma unroll
    for (int off = 1; off < 16; off <<= 1)
        #pragma unroll
        for (int r = 0; r < 4; ++r) {
            s[r] += __shfl_xor(s[r], off);
            q[r] += __shfl_xor(q[r], off);
        }
    #pragma unroll
    for (int r = 0; r < 4; ++r) {
        const int node = node0 + w * 16 + gq * 4 + r;
        if (node >= NN) continue;
        const float mean = s[r] * (1.0f / HID);
        const float var  = q[r] * (1.0f / HID) - mean * mean;
        const float rstd = rsqrtf(var + LN_EPS);
        #pragma unroll
        for (int c = 0; c < 8; ++c) {
            const float y = (acc[c][r] - mean) * rstd * gam[c] + bet[c];
            hb[(size_t)node * 128 + c * 16 + li] = f2bf(y);
            if (write_f32) hout[(size_t)node * 128 + c * 16 + li] = y;
        }
    }
}

extern "C" void kernel_launch(void* const* d_in, const int* in_sizes, int n_in,
                              void* d_out, int out_size, void* d_ws, size_t ws_size,
                              hipStream_t stream) {
    const float* node_feat = (const float*)d_in[0];
    const float* topo      = (const float*)d_in[1];
    const float* embed     = (const float*)d_in[2];
    const float* W_in      = (const float*)d_in[3];
    const float* b_in      = (const float*)d_in[4];
    const float* ln0_g     = (const float*)d_in[5];
    const float* ln0_b     = (const float*)d_in[6];
    const float* Wl        = (const float*)d_in[7];
    const float* bl        = (const float*)d_in[8];
    const float* Wr        = (const float*)d_in[9];
    const float* ln_g      = (const float*)d_in[10];
    const float* ln_b      = (const float*)d_in[11];
    const int*   opcode    = (const int*)d_in[12];
    const int*   edge      = (const int*)d_in[13];
    const int*   e_src = edge;
    const int*   e_tgt = edge + NE;

    float* h = (float*)d_out;   // final output 100000 x 128 f32

    char* w = (char*)d_ws;
    ushort* hb     = (ushort*)w;  w += (size_t)NN * HID * sizeof(ushort);   // 25.6 MB
    ushort* aggb   = (ushort*)w;  w += (size_t)NN * HID * sizeof(ushort);   // 25.6 MB
    float* inv_deg = (float*)w;   w += 400016;
    int*   offs    = (int*)w;     w += 400016;    // NN+1 ints
    int*   bhist   = (int*)w;     w += 1024;
    int*   bpos    = (int*)w;     w += 1024;
    int*   bcur    = (int*)w;     w += 1024;
    int*   csr     = (int*)w;     w += (size_t)NE * sizeof(int);            // 6.4 MB
    uint2* pairs   = (uint2*)w;   w += (size_t)NE * sizeof(uint2);          // 12.8 MB
    ushort* winp   = (ushort*)w;  w += 7 * 8 * 64 * 8 * sizeof(ushort);     // 57 KB
    ushort* wcat   = (ushort*)w;  w += 4 * 8 * 8 * 64 * 8 * sizeof(ushort); // 262 KB

    const int EBLK = (NE + 2047) / 2048;   // 782

    pack_weights_kernel<<<78, 256, 0, stream>>>(W_in, Wl, Wr, winp, wcat);

    input_proj_mfma<<<(NN + 63) / 64, 256, 0, stream>>>(
        node_feat, topo, embed, opcode, winp, b_in, ln0_g, ln0_b, hb);

    // CSR build (bucketed, no per-node global atomics)
    hipMemsetAsync(bhist, 0, NBUCK * sizeof(int), stream);
    hist_kernel<<<EBLK, 256, 0, stream>>>(e_tgt, bhist);
    bucket_scan_kernel<<<1, 256, 0, stream>>>(bhist, bpos, bcur);
    partition_kernel<<<EBLK, 256, 0, stream>>>(e_src, e_tgt, bcur, pairs);
    bucket_fill_kernel<<<NBUCK, 256, 0, stream>>>(pairs, bpos, bhist, offs, inv_deg, csr);

    for (int layer = 0; layer < 4; ++layer) {
        gather_kernel<<<NN / 4, 256, 0, stream>>>(hb, csr, offs, inv_deg, aggb);
        layer_mfma<<<(NN + 63) / 64, 256, 0, stream>>>(
            hb, aggb, wcat + (size_t)layer * 8 * 8 * 64 * 8,
            bl + (size_t)layer * HID,
            ln_g + (size_t)layer * HID, ln_b + (size_t)layer * HID,
            h, layer == 3 ? 1 : 0);
    }
}